// Round 3
// baseline (256.682 us; speedup 1.0000x reference)
//
#include <hip/hip_runtime.h>
#include <math.h>
#include <utility>

// predicted/target: (B,T,H,W,1) fp32
#define BB 8
#define TT 16
#define HH 256
#define WW 256
#define NPX (TT * HH * WW)      // 1,048,576 px per sample
#define CROWS 32                // output rows per ssim block
#define NCHUNK (HH / CROWS)     // 8
#define NBLK (BB * TT * NCHUNK) // 1024 ssim blocks

// ws float layout (per-block partials from k_reduce; 512 = 8 samples x 64 chunks)
#define P_MINP 0
#define P_MAXP 512
#define P_MINT 1024
#define P_MAXT 1536
#define P_SUMT 2048
#define WS_S   2560   // accumulated valid-weighted ssim sum

typedef float v2f __attribute__((ext_vector_type(2)));

template <int... J, typename F>
__device__ __forceinline__ void sf_impl(std::integer_sequence<int, J...>, F&& f) {
  (f(std::integral_constant<int, J>{}), ...);
}
template <int N, typename F>
__device__ __forceinline__ void static_for(F&& f) {
  sf_impl(std::make_integer_sequence<int, N>{}, (F&&)f);
}

// Gaussian taps, precomputed (exp(-(i-5)^2/4.5), normalized). Reference
// computes these in fp32; literals agree to ~1e-7 — far below threshold.
#define G0 0.0010283776f
#define G1 0.0075987582f
#define G2 0.0360008014f
#define G3 0.1093606427f
#define G4 0.2130055745f
#define G5 0.2660117857f
__device__ __constant__ const float c_g[11] = {G0, G1, G2, G3, G4, G5,
                                               G4, G3, G2, G1, G0};

// Per-sample min/max of pred & targ + sum(targ), one partial per block.
__global__ __launch_bounds__(256) void k_reduce(const float* __restrict__ p,
                                                const float* __restrict__ t,
                                                float* __restrict__ wsf) {
  const int b = blockIdx.x >> 6;
  const size_t base = (size_t)b * NPX + (size_t)(blockIdx.x & 63) * (NPX / 64);
  const int tid = threadIdx.x;

  float mnp = 3.4e38f, mxp = -3.4e38f, mnt = 3.4e38f, mxt = -3.4e38f, st = 0.f;
  const float4* p4 = (const float4*)(p + base);
  const float4* t4 = (const float4*)(t + base);
#pragma unroll 4
  for (int it = 0; it < 16; ++it) {
    float4 a = p4[it * 256 + tid];
    float4 c = t4[it * 256 + tid];
    mnp = fminf(mnp, fminf(fminf(a.x, a.y), fminf(a.z, a.w)));
    mxp = fmaxf(mxp, fmaxf(fmaxf(a.x, a.y), fmaxf(a.z, a.w)));
    mnt = fminf(mnt, fminf(fminf(c.x, c.y), fminf(c.z, c.w)));
    mxt = fmaxf(mxt, fmaxf(fmaxf(c.x, c.y), fmaxf(c.z, c.w)));
    st += c.x + c.y + c.z + c.w;
  }
  for (int off = 32; off > 0; off >>= 1) {
    mnp = fminf(mnp, __shfl_down(mnp, off));
    mxp = fmaxf(mxp, __shfl_down(mxp, off));
    mnt = fminf(mnt, __shfl_down(mnt, off));
    mxt = fmaxf(mxt, __shfl_down(mxt, off));
    st += __shfl_down(st, off);
  }
  __shared__ float s_mnp[4], s_mxp[4], s_mnt[4], s_mxt[4], s_st[4];
  int wave = tid >> 6, lane = tid & 63;
  if (lane == 0) {
    s_mnp[wave] = mnp; s_mxp[wave] = mxp;
    s_mnt[wave] = mnt; s_mxt[wave] = mxt; s_st[wave] = st;
  }
  __syncthreads();
  if (tid == 0) {
    for (int w = 1; w < 4; ++w) {
      mnp = fminf(mnp, s_mnp[w]); mxp = fmaxf(mxp, s_mxp[w]);
      mnt = fminf(mnt, s_mnt[w]); mxt = fmaxf(mxt, s_mxt[w]);
      st += s_st[w];
    }
    wsf[P_MINP + blockIdx.x] = mnp;
    wsf[P_MAXP + blockIdx.x] = mxp;
    wsf[P_MINT + blockIdx.x] = mnt;
    wsf[P_MAXT + blockIdx.x] = mxt;
    wsf[P_SUMT + blockIdx.x] = st;
    if (blockIdx.x == 0) wsf[WS_S] = 0.f;
  }
}

// Fused separable-conv SSIM. Block = one image x one 32-row chunk; thread =
// one column. Rows staged as interleaved (t,p) float2 in LDS (b64 ops,
// packed v_pk_fma math). Row loop unrolled in groups of 22 = lcm(2,11) so
// LDS buffer parity (i&1) and ring slot (i%11) are compile-time constants —
// the 55-float ring stays in registers (round-2 version spilled: 23.6 MB
// scratch writes at VGPR=64).
__global__ __launch_bounds__(256, 2) void k_ssim(const float* __restrict__ pred,
                                                 const float* __restrict__ targ,
                                                 float* __restrict__ wsf) {
  const int img = blockIdx.x >> 3;    // 0..127
  const int chunk = blockIdx.x & 7;   // 0..7
  const int b = img >> 4;             // sample
  const int x = threadIdx.x;
  const int y0 = chunk * CROWS;
  const float* tptr = targ + (size_t)img * (HH * WW);
  const float* pptr = pred + (size_t)img * (HH * WW);

  // Preamble: reduce this sample's 64 partials -> norm params + valid (wave 0)
  __shared__ float sprm[5];  // ps, pb, ts, tb, valid
  if (x < 64) {
    float mnp = wsf[P_MINP + b * 64 + x];
    float mxp = wsf[P_MAXP + b * 64 + x];
    float mnt = wsf[P_MINT + b * 64 + x];
    float mxt = wsf[P_MAXT + b * 64 + x];
    float st  = wsf[P_SUMT + b * 64 + x];
    for (int off = 32; off > 0; off >>= 1) {
      mnp = fminf(mnp, __shfl_down(mnp, off));
      mxp = fmaxf(mxp, __shfl_down(mxp, off));
      mnt = fminf(mnt, __shfl_down(mnt, off));
      mxt = fmaxf(mxt, __shfl_down(mxt, off));
      st += __shfl_down(st, off);
    }
    if (x == 0) {
      float ps = 1.f / fmaxf(mxp - mnp, 1e-6f);
      float tsc = 1.f / fmaxf(mxt - mnt, 1e-6f);
      sprm[0] = ps; sprm[1] = -mnp * ps;
      sprm[2] = tsc; sprm[3] = -mnt * tsc;
      sprm[4] = (st != 0.f) ? 1.f : 0.f;
    }
  }

  // Double-buffered staging rows of (t,p) float2, 5-wide zero halos.
  __shared__ v2f srow[2][WW + 12];
  if (x < 5) {
    v2f z = {0.f, 0.f};
    srow[0][x] = z; srow[1][x] = z;
    srow[0][WW + 5 + x] = z; srow[1][WW + 5 + x] = z;
  }
  __syncthreads();
  const float ps = sprm[0], pb = sprm[1], ts = sprm[2], tb = sprm[3];

  // Register ring: h-conv results for 11 rows. (mu_t,mu_p), (t2,p2), tp.
  v2f r_mu[11], r_sq[11];
  float r_tp[11];
  float acc = 0.f;
  const int ystart = y0 - 5;  // iter i stages row ystart+i; output yo = row-5
  const float C1 = 1e-4f, C2 = 9e-4f, C3 = 4.5e-4f;

#pragma unroll 1
  for (int grp = 0; grp < 2; ++grp) {
    const int ibase = grp * 22;
    static_for<22>([&](auto jc) {
      constexpr int j = decltype(jc)::value;
      constexpr int buf = j & 1;     // compile-time: 22 is even
      constexpr int slot = j % 11;   // compile-time: 22 % 11 == 0
      const int i = ibase + j;
      if (i < 42) {  // block-uniform (folds to true for j<20, grp check else)
        const int y = ystart + i;
        const int yc = min(max(y, 0), HH - 1);
        const bool in = (unsigned)y < (unsigned)HH;
        float traw = tptr[(size_t)yc * WW + x];
        float praw = pptr[(size_t)yc * WW + x];
        v2f nv;
        nv.x = in ? fmaf(traw, ts, tb) : 0.f;
        nv.y = in ? fmaf(praw, ps, pb) : 0.f;
        srow[buf][x + 5] = nv;
        __syncthreads();

        v2f mu = {0.f, 0.f}, sq = {0.f, 0.f};
        float tp = 0.f;
        static_for<11>([&](auto kc) {
          constexpr int k = decltype(kc)::value;
          constexpr float gk = (k == 0 || k == 10) ? G0
                             : (k == 1 || k == 9) ? G1
                             : (k == 2 || k == 8) ? G2
                             : (k == 3 || k == 7) ? G3
                             : (k == 4 || k == 6) ? G4 : G5;
          v2f v = srow[buf][x + k];
          v2f g2 = {gk, gk};
          v2f w = g2 * v;                              // (g*t, g*p)
          mu = mu + w;                                 // Σg*t, Σg*p
          sq = __builtin_elementwise_fma(w, v, sq);    // Σg*t², Σg*p²
          tp = fmaf(w.x, v.y, tp);                     // Σg*t*p
        });
        r_mu[slot] = mu; r_sq[slot] = sq; r_tp[slot] = tp;

        if (i >= 10) {  // block-uniform: outputs yo = y0..y0+31
          v2f vmu = {0.f, 0.f}, vsq = {0.f, 0.f};
          float vtp = 0.f;
          static_for<11>([&](auto kc) {
            constexpr int k = decltype(kc)::value;
            constexpr int s = (j + 1 + k) % 11;  // compile-time ring index
            constexpr float gk = (k == 0 || k == 10) ? G0
                               : (k == 1 || k == 9) ? G1
                               : (k == 2 || k == 8) ? G2
                               : (k == 3 || k == 7) ? G3
                               : (k == 4 || k == 6) ? G4 : G5;
            v2f g2 = {gk, gk};
            vmu = __builtin_elementwise_fma(g2, r_mu[s], vmu);
            vsq = __builtin_elementwise_fma(g2, r_sq[s], vsq);
            vtp = fmaf(gk, r_tp[s], vtp);
          });
          float m1 = vmu.x, m2 = vmu.y;
          float mu11 = m1 * m1, mu22 = m2 * m2, m12 = m1 * m2;
          float s1 = fmaxf(vsq.x - mu11, 1e-6f);
          float s2 = fmaxf(vsq.y - mu22, 1e-6f);
          float s12 = vtp - m12;
          float root = sqrtf(s1 * s2);
          // lum*con*str = [num1*num2*(s12+C3)] / [den1*den2*(root+C3)]
          float num = fmaf(2.f, m12, C1) * fmaf(2.f, root, C2) * (s12 + C3);
          float den = (mu11 + mu22 + C1) * (s1 + s2 + C2) * (root + C3);
          acc = fmaf(num, __builtin_amdgcn_rcpf(den), acc);
        }
      }
    });
  }

  // Block reduction + valid-weighted accumulate
  for (int off = 32; off > 0; off >>= 1) acc += __shfl_down(acc, off);
  __shared__ float sred[4];
  if ((x & 63) == 0) sred[x >> 6] = acc;
  __syncthreads();
  if (x == 0) {
    float v = sred[0] + sred[1] + sred[2] + sred[3];
    atomicAdd(&wsf[WS_S], v * sprm[4]);
  }
}

__global__ void k_loss(const float* __restrict__ wsf, float* __restrict__ out) {
  const int c = threadIdx.x;  // 64 threads
  float sums[8];
#pragma unroll
  for (int b = 0; b < 8; ++b) sums[b] = wsf[P_SUMT + b * 64 + c];
  for (int off = 32; off > 0; off >>= 1) {
#pragma unroll
    for (int b = 0; b < 8; ++b) sums[b] += __shfl_down(sums[b], off);
  }
  if (c == 0) {
    float sv = 0.f;
#pragma unroll
    for (int b = 0; b < 8; ++b) sv += (sums[b] != 0.f) ? 1.f : 0.f;
    float S = wsf[WS_S];
    out[0] = (sv - S * (1.f / (float)NPX)) / fmaxf(sv, 1.f);
  }
}

extern "C" void kernel_launch(void* const* d_in, const int* in_sizes, int n_in,
                              void* d_out, int out_size, void* d_ws, size_t ws_size,
                              hipStream_t stream) {
  const float* pred = (const float*)d_in[0];
  const float* targ = (const float*)d_in[1];
  float* wsf = (float*)d_ws;
  float* out = (float*)d_out;

  hipLaunchKernelGGL(k_reduce, dim3(512), dim3(256), 0, stream, pred, targ, wsf);
  hipLaunchKernelGGL(k_ssim, dim3(NBLK), dim3(256), 0, stream, pred, targ, wsf);
  hipLaunchKernelGGL(k_loss, dim3(1), dim3(64), 0, stream, wsf, out);
}

// Round 4
// 132.474 us; speedup vs baseline: 1.9376x; 1.9376x over previous
//
#include <hip/hip_runtime.h>
#include <math.h>

// predicted/target: (B,T,H,W,1) fp32
#define BB 8
#define TT 16
#define HH 256
#define WW 256
#define NPX (TT * HH * WW)      // 1,048,576 px per sample
#define CROWS 32                // output rows per ssim block
#define NBLK (BB * TT * (HH / CROWS)) // 1024 ssim blocks

// ws float layout (per-block partials from k_reduce; 512 = 8 samples x 64 chunks)
#define P_MINP 0
#define P_MAXP 512
#define P_MINT 1024
#define P_MAXT 1536
#define P_SUMT 2048
#define WS_S   2560   // accumulated valid-weighted ssim sum

typedef float v2f __attribute__((ext_vector_type(2)));

// Gaussian taps (exp(-(i-5)^2/4.5), normalized) as literals.
#define G0 0.0010283776f
#define G1 0.0075987582f
#define G2 0.0360008014f
#define G3 0.1093606427f
#define G4 0.2130055745f
#define G5 0.2660117857f
// tap k -> weight; constant-folds after the 11-tap loops are unrolled
#define GA_(k) ((k) == 0 || (k) == 10 ? G0 : (k) == 1 || (k) == 9 ? G1 \
              : (k) == 2 || (k) == 8 ? G2 : (k) == 3 || (k) == 7 ? G3 \
              : (k) == 4 || (k) == 6 ? G4 : G5)

// Per-sample min/max of pred & targ + sum(targ), one partial per block.
__global__ __launch_bounds__(256) void k_reduce(const float* __restrict__ p,
                                                const float* __restrict__ t,
                                                float* __restrict__ wsf) {
  const int b = blockIdx.x >> 6;
  const size_t base = (size_t)b * NPX + (size_t)(blockIdx.x & 63) * (NPX / 64);
  const int tid = threadIdx.x;

  float mnp = 3.4e38f, mxp = -3.4e38f, mnt = 3.4e38f, mxt = -3.4e38f, st = 0.f;
  const float4* p4 = (const float4*)(p + base);
  const float4* t4 = (const float4*)(t + base);
#pragma unroll 4
  for (int it = 0; it < 16; ++it) {
    float4 a = p4[it * 256 + tid];
    float4 c = t4[it * 256 + tid];
    mnp = fminf(mnp, fminf(fminf(a.x, a.y), fminf(a.z, a.w)));
    mxp = fmaxf(mxp, fmaxf(fmaxf(a.x, a.y), fmaxf(a.z, a.w)));
    mnt = fminf(mnt, fminf(fminf(c.x, c.y), fminf(c.z, c.w)));
    mxt = fmaxf(mxt, fmaxf(fmaxf(c.x, c.y), fmaxf(c.z, c.w)));
    st += c.x + c.y + c.z + c.w;
  }
  for (int off = 32; off > 0; off >>= 1) {
    mnp = fminf(mnp, __shfl_down(mnp, off));
    mxp = fmaxf(mxp, __shfl_down(mxp, off));
    mnt = fminf(mnt, __shfl_down(mnt, off));
    mxt = fmaxf(mxt, __shfl_down(mxt, off));
    st += __shfl_down(st, off);
  }
  __shared__ float s_mnp[4], s_mxp[4], s_mnt[4], s_mxt[4], s_st[4];
  int wave = tid >> 6, lane = tid & 63;
  if (lane == 0) {
    s_mnp[wave] = mnp; s_mxp[wave] = mxp;
    s_mnt[wave] = mnt; s_mxt[wave] = mxt; s_st[wave] = st;
  }
  __syncthreads();
  if (tid == 0) {
    for (int w = 1; w < 4; ++w) {
      mnp = fminf(mnp, s_mnp[w]); mxp = fmaxf(mxp, s_mxp[w]);
      mnt = fminf(mnt, s_mnt[w]); mxt = fmaxf(mxt, s_mxt[w]);
      st += s_st[w];
    }
    wsf[P_MINP + blockIdx.x] = mnp;
    wsf[P_MAXP + blockIdx.x] = mxp;
    wsf[P_MINT + blockIdx.x] = mnt;
    wsf[P_MAXT + blockIdx.x] = mxt;
    wsf[P_SUMT + blockIdx.x] = st;
    if (blockIdx.x == 0) wsf[WS_S] = 0.f;
  }
}

// One row-step of the fused separable SSIM pipeline. J is a literal, so
// buffer parity, ring slot, and output guard are compile-time; the 11-tap
// loops fully unroll; the ring arrays see only constant indices and no
// lambda captures -> SROA keeps them in VGPRs (r1-r3 all spilled).
// One-step register prefetch (tnxt/pnxt) hides global-load latency;
// sched_barrier(0) stops the scheduler hoisting 40+ loads to the top.
#define STEP(J) do {                                                         \
    constexpr int jj = (J);                                                  \
    constexpr int buf = jj & 1;                                              \
    constexpr int slot = jj % 11;                                            \
    const bool in = (unsigned)(ystart + jj) < (unsigned)HH;                  \
    v2f nv;                                                                  \
    nv.x = in ? fmaf(tcur, ts, tb) : 0.f;                                    \
    nv.y = in ? fmaf(pcur, ps, pb) : 0.f;                                    \
    srow[buf][x + 5] = nv;                                                   \
    if constexpr (jj < 41) {                                                 \
      const int yn = min(max(ystart + jj + 1, 0), HH - 1);                   \
      tnxt = tptr[(size_t)yn * WW + x];                                      \
      pnxt = pptr[(size_t)yn * WW + x];                                      \
    }                                                                        \
    __syncthreads();                                                         \
    v2f hmu = {0.f, 0.f}, hsq = {0.f, 0.f};                                  \
    float htp = 0.f;                                                         \
    _Pragma("unroll")                                                        \
    for (int k = 0; k < 11; ++k) {                                           \
      v2f v = srow[buf][x + k];                                              \
      v2f g2 = {GA_(k), GA_(k)};                                             \
      v2f w = g2 * v;                                                        \
      hmu = hmu + w;                                                         \
      hsq = __builtin_elementwise_fma(w, v, hsq);                            \
      htp = fmaf(w.x, v.y, htp);                                             \
    }                                                                        \
    r_mu[slot] = hmu; r_sq[slot] = hsq; r_tp[slot] = htp;                    \
    if constexpr (jj >= 10) {                                                \
      v2f vmu = {0.f, 0.f}, vsq = {0.f, 0.f};                                \
      float vtp = 0.f;                                                       \
      _Pragma("unroll")                                                      \
      for (int k = 0; k < 11; ++k) {                                         \
        const int s = (jj + 1 + k) % 11;                                     \
        v2f g2 = {GA_(k), GA_(k)};                                           \
        vmu = __builtin_elementwise_fma(g2, r_mu[s], vmu);                   \
        vsq = __builtin_elementwise_fma(g2, r_sq[s], vsq);                   \
        vtp = fmaf(GA_(k), r_tp[s], vtp);                                    \
      }                                                                      \
      float m1 = vmu.x, m2 = vmu.y;                                          \
      float mu11 = m1 * m1, mu22 = m2 * m2, m12 = m1 * m2;                   \
      float s1 = fmaxf(vsq.x - mu11, 1e-6f);                                 \
      float s2 = fmaxf(vsq.y - mu22, 1e-6f);                                 \
      float s12 = vtp - m12;                                                 \
      float root = sqrtf(s1 * s2);                                           \
      float num = fmaf(2.f, m12, C1) * fmaf(2.f, root, C2) * (s12 + C3);     \
      float den = (mu11 + mu22 + C1) * (s1 + s2 + C2) * (root + C3);         \
      acc = fmaf(num, __builtin_amdgcn_rcpf(den), acc);                      \
    }                                                                        \
    tcur = tnxt; pcur = pnxt;                                                \
    __builtin_amdgcn_sched_barrier(0);                                       \
  } while (0)

__global__ __launch_bounds__(256, 3) void k_ssim(const float* __restrict__ pred,
                                                 const float* __restrict__ targ,
                                                 float* __restrict__ wsf) {
  const int img = blockIdx.x >> 3;    // 0..127
  const int chunk = blockIdx.x & 7;   // 0..7
  const int b = img >> 4;             // sample
  const int x = threadIdx.x;
  const int y0 = chunk * CROWS;
  const float* tptr = targ + (size_t)img * (HH * WW);
  const float* pptr = pred + (size_t)img * (HH * WW);

  // Preamble: reduce this sample's 64 partials -> norm params + valid (wave 0)
  __shared__ float sprm[5];  // ps, pb, ts, tb, valid
  if (x < 64) {
    float mnp = wsf[P_MINP + b * 64 + x];
    float mxp = wsf[P_MAXP + b * 64 + x];
    float mnt = wsf[P_MINT + b * 64 + x];
    float mxt = wsf[P_MAXT + b * 64 + x];
    float st  = wsf[P_SUMT + b * 64 + x];
    for (int off = 32; off > 0; off >>= 1) {
      mnp = fminf(mnp, __shfl_down(mnp, off));
      mxp = fmaxf(mxp, __shfl_down(mxp, off));
      mnt = fminf(mnt, __shfl_down(mnt, off));
      mxt = fmaxf(mxt, __shfl_down(mxt, off));
      st += __shfl_down(st, off);
    }
    if (x == 0) {
      float psv = 1.f / fmaxf(mxp - mnp, 1e-6f);
      float tsv = 1.f / fmaxf(mxt - mnt, 1e-6f);
      sprm[0] = psv; sprm[1] = -mnp * psv;
      sprm[2] = tsv; sprm[3] = -mnt * tsv;
      sprm[4] = (st != 0.f) ? 1.f : 0.f;
    }
  }

  // Double-buffered staging rows of (t,p) float2, 5-wide zero halos.
  __shared__ v2f srow[2][WW + 12];
  if (x < 5) {
    v2f z = {0.f, 0.f};
    srow[0][x] = z; srow[1][x] = z;
    srow[0][WW + 5 + x] = z; srow[1][WW + 5 + x] = z;
  }
  __syncthreads();
  const float ps = sprm[0], pb = sprm[1], ts = sprm[2], tb = sprm[3];

  // Ring: h-conv results for 11 rows; only constant indices -> registers.
  v2f r_mu[11], r_sq[11];
  float r_tp[11];
  float acc = 0.f;
  const int ystart = y0 - 5;  // step j stages row ystart+j; output yo = row-5
  const float C1 = 1e-4f, C2 = 9e-4f, C3 = 4.5e-4f;

  // Prime the 1-step prefetch
  float tcur, pcur, tnxt = 0.f, pnxt = 0.f;
  {
    const int yc = min(max(ystart, 0), HH - 1);
    tcur = tptr[(size_t)yc * WW + x];
    pcur = pptr[(size_t)yc * WW + x];
  }

  STEP(0);  STEP(1);  STEP(2);  STEP(3);  STEP(4);  STEP(5);  STEP(6);
  STEP(7);  STEP(8);  STEP(9);  STEP(10); STEP(11); STEP(12); STEP(13);
  STEP(14); STEP(15); STEP(16); STEP(17); STEP(18); STEP(19); STEP(20);
  STEP(21); STEP(22); STEP(23); STEP(24); STEP(25); STEP(26); STEP(27);
  STEP(28); STEP(29); STEP(30); STEP(31); STEP(32); STEP(33); STEP(34);
  STEP(35); STEP(36); STEP(37); STEP(38); STEP(39); STEP(40); STEP(41);

  // Block reduction + valid-weighted accumulate
  for (int off = 32; off > 0; off >>= 1) acc += __shfl_down(acc, off);
  __shared__ float sred[4];
  if ((x & 63) == 0) sred[x >> 6] = acc;
  __syncthreads();
  if (x == 0) {
    float v = sred[0] + sred[1] + sred[2] + sred[3];
    atomicAdd(&wsf[WS_S], v * sprm[4]);
  }
}

__global__ void k_loss(const float* __restrict__ wsf, float* __restrict__ out) {
  const int c = threadIdx.x;  // 64 threads
  float sums[8];
#pragma unroll
  for (int b = 0; b < 8; ++b) sums[b] = wsf[P_SUMT + b * 64 + c];
  for (int off = 32; off > 0; off >>= 1) {
#pragma unroll
    for (int b = 0; b < 8; ++b) sums[b] += __shfl_down(sums[b], off);
  }
  if (c == 0) {
    float sv = 0.f;
#pragma unroll
    for (int b = 0; b < 8; ++b) sv += (sums[b] != 0.f) ? 1.f : 0.f;
    float S = wsf[WS_S];
    out[0] = (sv - S * (1.f / (float)NPX)) / fmaxf(sv, 1.f);
  }
}

extern "C" void kernel_launch(void* const* d_in, const int* in_sizes, int n_in,
                              void* d_out, int out_size, void* d_ws, size_t ws_size,
                              hipStream_t stream) {
  const float* pred = (const float*)d_in[0];
  const float* targ = (const float*)d_in[1];
  float* wsf = (float*)d_ws;
  float* out = (float*)d_out;

  hipLaunchKernelGGL(k_reduce, dim3(512), dim3(256), 0, stream, pred, targ, wsf);
  hipLaunchKernelGGL(k_ssim, dim3(NBLK), dim3(256), 0, stream, pred, targ, wsf);
  hipLaunchKernelGGL(k_loss, dim3(1), dim3(64), 0, stream, wsf, out);
}